// Round 4
// baseline (218.722 us; speedup 1.0000x reference)
//
#include <hip/hip_runtime.h>

// ---------------------------------------------------------------------------
// Fused 5-layer GRU (SEQ=1, h0=0) + FC for MI355X (gfx950).  Round 5.
//
// R5: replace the per-layer LDS round-trip (4 ds_write_b64 + lgkmcnt(0) +
// 2 ds_read_b128, ~150 cyc serial latency each layer) with an in-register
// C->B fragment transform using gfx950's v_permlane32_swap_b32 +
// v_permlane16_swap_b32 (pure VALU, no LDS pipe):
//   C layout: lane (n0,q') holds h[batch=n0][hid=4q'+i], i=0..3 (+16 plane).
//   B layout: lane (n0,q)  needs h[batch=n0][hid=8q..8q+7].
//   With packed words X=hw0 (hids 4a..4a+1), Y=hw2 (hids 16+4a..+1):
//   permlane32_swap(X,Y) -> [X0,X1,Y0,Y1],[X2,X3,Y2,Y3]; then
//   permlane16_swap      -> [X0,X2,Y0,Y2] = B word0, [X1,X3,Y1,Y3] = word2.
//   4 pairs x 2 ops = 8 VALU ops per layer replace 6 LDS ops + wait.
// hbuf deleted: LDS 64.1 -> 43.6 KB -> 3 blocks/CU (24 waves, launch_bounds
// (512,6)); all asm barriers in the loop removed (no LDS writes in loop).
//
// Kept from R4: W_ST=40-padded LDS weights ((5*n0+q)%8 uniform bank quads),
// packed f32x2 activation math (v_pk_*), split-B bf16 hi+lo precision.
//
// Orientation: C^T = W @ h^T  (A = weight tile [gate][k], B = h^T [k][batch]).
// MFMA C/D layout (16x16x32): col = lane&15 = BATCH, row = q*4+i = gate row.
// ---------------------------------------------------------------------------

typedef __attribute__((ext_vector_type(8))) short bf16x8;
typedef __attribute__((ext_vector_type(4))) float f32x4;
typedef __attribute__((ext_vector_type(2))) float f32x2;
typedef __attribute__((ext_vector_type(4))) unsigned int u32x4;

#define NLAYER 5
#define W_ST   40  // weight row stride in bf16 (80 B = 5 bank-quads: conflict-free)
#define NT     512 // block threads (8 waves)

__device__ __forceinline__ float fexp2(float x) {
#if __has_builtin(__builtin_amdgcn_exp2f)
    return __builtin_amdgcn_exp2f(x);
#else
    return exp2f(x);
#endif
}
__device__ __forceinline__ float frcp(float x) {
#if __has_builtin(__builtin_amdgcn_rcpf)
    return __builtin_amdgcn_rcpf(x);
#else
    return 1.0f / x;
#endif
}

__device__ __forceinline__ unsigned short bf_rne(float f) {
    union { float f; unsigned u; } v; v.f = f;
    unsigned r = v.u + 0x7fffu + ((v.u >> 16) & 1u);
    return (unsigned short)(r >> 16);
}

// Truncation-based split: f ~= bf16(hi) + bf16(lo), packing two consecutive
// elements into one hi word and one lo word (low short = even element).
// Combined rel error < 2^-15, negligible vs 2^-8 weight quant.
__device__ __forceinline__ void split2(float f0, float f1, unsigned &hi, unsigned &lo) {
    unsigned u0 = __float_as_uint(f0), u1 = __float_as_uint(f1);
    unsigned h0 = u0 & 0xffff0000u, h1 = u1 & 0xffff0000u;
    hi = (u0 >> 16) | h1;
    float r0 = f0 - __uint_as_float(h0);        // exact
    float r1 = f1 - __uint_as_float(h1);        // exact
    lo = (__float_as_uint(r0) >> 16) | (__float_as_uint(r1) & 0xffff0000u);
}

__device__ __forceinline__ f32x4 mfma16(bf16x8 a, bf16x8 b, f32x4 c) {
    return __builtin_amdgcn_mfma_f32_16x16x32_bf16(a, b, c, 0, 0, 0);
}

// In-register 16-lane-group exchange (gfx950):
//   in : x = [X0,X1,X2,X3], y = [Y0,Y1,Y2,Y3]   (16-lane groups)
//   out: x = [X0,X2,Y0,Y2], y = [X1,X3,Y1,Y3]
__device__ __forceinline__ void xpose_pair(unsigned &x, unsigned &y) {
    asm("v_permlane32_swap_b32 %0, %1" : "+v"(x), "+v"(y));
    asm("v_permlane16_swap_b32 %0, %1" : "+v"(x), "+v"(y));
}

__device__ __forceinline__ f32x2 mk2(float a, float b) { f32x2 v; v.x = a; v.y = b; return v; }
__device__ __forceinline__ f32x2 exp2v(f32x2 v) { f32x2 r; r.x = fexp2(v.x); r.y = fexp2(v.y); return r; }
__device__ __forceinline__ f32x2 rcpv(f32x2 v)  { f32x2 r; r.x = frcp(v.x);  r.y = frcp(v.y);  return r; }

// h = (1-z)*n = sigmoid(-az) * tanh(an + sigmoid(ar)*cn)
//   = [ez*(1-en)] / [(1+ez)*(1+en)],  ez=e^{-az}, en=e^{-2(an+r*cn)}
// Packed 2-wide: non-trans ops lower to v_pk_* VOP3P.
__device__ __forceinline__ f32x2 gru_act2(f32x2 ar, f32x2 az, f32x2 an, f32x2 cn) {
    const float NL2E = -1.4426950408889634f;
    f32x2 er  = exp2v(ar * NL2E);
    f32x2 ez  = exp2v(az * NL2E);
    f32x2 r   = rcpv(er + 1.0f);
    f32x2 a2  = an + r * cn;
    f32x2 en  = exp2v(a2 * (2.0f * NL2E));
    f32x2 num = ez - ez * en;
    f32x2 den = (ez + 1.0f) * (en + 1.0f);
    return num * rcpv(den);
}

struct __align__(16) Lds {
    unsigned short wA[NLAYER * 96 * W_ST];        // 38400 B  [l][gate-row][k], row stride 40
    unsigned short wF[32 * W_ST];                 //  2560 B  fc_w rows, stride 40
    float bsum[NLAYER * 96];                      //  1920 B  r,z: b_ih+b_hh ; n: b_ih only
    float cn_[NLAYER * 32];                       //   640 B  b_hh n-gate
    float fb_[32];                                //   128 B  fc_b
};                                                // total 43648 B -> 3 blocks/CU

union BU { u32x4 w; bf16x8 v; };

__global__ __launch_bounds__(NT, 6) void gru_fused(
    const float* __restrict__ x, const float* __restrict__ w_ih,
    const float* __restrict__ b_ih, const float* __restrict__ b_hh,
    const float* __restrict__ fc_w, const float* __restrict__ fc_b,
    float* __restrict__ out, int nTiles)
{
    __shared__ Lds s;
    const int tid = threadIdx.x;

    // ---- stage weights / biases into LDS (once per block) ----
    for (int i = tid; i < NLAYER * 96 * 32; i += NT) {
        int r = i >> 5, c = i & 31;
        s.wA[r * W_ST + c] = bf_rne(w_ih[i]);
    }
    for (int i = tid; i < 32 * 32; i += NT) {
        int r = i >> 5, c = i & 31;
        s.wF[r * W_ST + c] = bf_rne(fc_w[i]);
    }
    for (int i = tid; i < NLAYER * 96; i += NT) {
        int c = i % 96;
        s.bsum[i] = b_ih[i] + (c < 64 ? b_hh[i] : 0.0f);
    }
    for (int i = tid; i < NLAYER * 32; i += NT) {
        int l = i >> 5, c = i & 31;
        s.cn_[i] = b_hh[l * 96 + 64 + c];
    }
    if (tid < 32) s.fb_[tid] = fc_b[tid];
    __syncthreads();

    const int lane = tid & 63;
    const int n0 = lane & 15;     // batch-col (B n-index / C col); A row m
    const int q  = lane >> 4;     // k-group (A/B), row-group (C/D)

    const int waveId  = (int)((blockIdx.x * (unsigned)NT + tid) >> 6);
    const int nWavesG = (int)((gridDim.x * (unsigned)NT) >> 6);

    for (int tile = waveId; tile < nTiles; tile += nWavesG) {
        const int rowBase = tile * 16;

        // ---- load x as B-frag: batch = rowBase+n0, k = q*8..q*8+7, split ----
        const float* xp = x + (size_t)(rowBase + n0) * 32 + q * 8;
        f32x4 xa = *(const f32x4*)xp;
        f32x4 xb = *(const f32x4*)(xp + 4);
        BU H, L;
        {
            unsigned th0, tl0, th1, tl1, th2, tl2, th3, tl3;
            split2(xa[0], xa[1], th0, tl0);
            split2(xa[2], xa[3], th1, tl1);
            split2(xb[0], xb[1], th2, tl2);
            split2(xb[2], xb[3], th3, tl3);
            H.w[0] = th0; H.w[1] = th1; H.w[2] = th2; H.w[3] = th3;
            L.w[0] = tl0; L.w[1] = tl1; L.w[2] = tl2; L.w[3] = tl3;
        }
        bf16x8 bHi = H.v, bLo = L.v;

        #pragma unroll
        for (int l = 0; l < NLAYER; ++l) {
            const unsigned short* wb = s.wA + l * 96 * W_ST;
            bf16x8 a0 = *(const bf16x8*)(wb + (0 * 16 + n0) * W_ST + q * 8);
            bf16x8 a1 = *(const bf16x8*)(wb + (1 * 16 + n0) * W_ST + q * 8);
            bf16x8 a2 = *(const bf16x8*)(wb + (2 * 16 + n0) * W_ST + q * 8);
            bf16x8 a3 = *(const bf16x8*)(wb + (3 * 16 + n0) * W_ST + q * 8);
            bf16x8 a4 = *(const bf16x8*)(wb + (4 * 16 + n0) * W_ST + q * 8);
            bf16x8 a5 = *(const bf16x8*)(wb + (5 * 16 + n0) * W_ST + q * 8);

            // acc init = bias f32x4 (rows q*4..q*4+3 of each 16-row gate tile)
            const float* bs = s.bsum + l * 96;
            f32x4 cR0 = *(const f32x4*)(bs + 0  + q * 4);
            f32x4 cR1 = *(const f32x4*)(bs + 16 + q * 4);
            f32x4 cZ0 = *(const f32x4*)(bs + 32 + q * 4);
            f32x4 cZ1 = *(const f32x4*)(bs + 48 + q * 4);
            f32x4 cN0 = *(const f32x4*)(bs + 64 + q * 4);
            f32x4 cN1 = *(const f32x4*)(bs + 80 + q * 4);
            f32x4 vc0 = *(const f32x4*)(s.cn_ + l * 32 + 0  + q * 4);
            f32x4 vc1 = *(const f32x4*)(s.cn_ + l * 32 + 16 + q * 4);

            cR0 = mfma16(a0, bLo, cR0); cR0 = mfma16(a0, bHi, cR0);
            cR1 = mfma16(a1, bLo, cR1); cR1 = mfma16(a1, bHi, cR1);
            cZ0 = mfma16(a2, bLo, cZ0); cZ0 = mfma16(a2, bHi, cZ0);
            cZ1 = mfma16(a3, bLo, cZ1); cZ1 = mfma16(a3, bHi, cZ1);
            cN0 = mfma16(a4, bLo, cN0); cN0 = mfma16(a4, bHi, cN0);
            cN1 = mfma16(a5, bLo, cN1); cN1 = mfma16(a5, bHi, cN1);

            // ---- activations (packed pairs): hid = q*4+i (+16), batch = n0 ----
            f32x2 hA = gru_act2(mk2(cR0[0], cR0[1]), mk2(cZ0[0], cZ0[1]),
                                mk2(cN0[0], cN0[1]), mk2(vc0[0], vc0[1]));
            f32x2 hB = gru_act2(mk2(cR0[2], cR0[3]), mk2(cZ0[2], cZ0[3]),
                                mk2(cN0[2], cN0[3]), mk2(vc0[2], vc0[3]));
            f32x2 hC = gru_act2(mk2(cR1[0], cR1[1]), mk2(cZ1[0], cZ1[1]),
                                mk2(cN1[0], cN1[1]), mk2(vc1[0], vc1[1]));
            f32x2 hD = gru_act2(mk2(cR1[2], cR1[3]), mk2(cZ1[2], cZ1[3]),
                                mk2(cN1[2], cN1[3]), mk2(vc1[2], vc1[3]));

            // ---- pack + in-register C->B transform (no LDS) ----
            // hw0 = hids 4q+{0,1}, hw1 = 4q+{2,3}, hw2 = 16+4q+{0,1}, hw3 = 16+4q+{2,3}
            unsigned hw0, hw1, hw2, hw3, lw0, lw1, lw2, lw3;
            split2(hA.x, hA.y, hw0, lw0);
            split2(hB.x, hB.y, hw1, lw1);
            split2(hC.x, hC.y, hw2, lw2);
            split2(hD.x, hD.y, hw3, lw3);
            xpose_pair(hw0, hw2);   // hw0 -> B elems {0,1}, hw2 -> elems {4,5}
            xpose_pair(hw1, hw3);   // hw1 -> B elems {2,3}, hw3 -> elems {6,7}
            xpose_pair(lw0, lw2);
            xpose_pair(lw1, lw3);
            H.w[0] = hw0; H.w[1] = hw1; H.w[2] = hw2; H.w[3] = hw3;
            L.w[0] = lw0; L.w[1] = lw1; L.w[2] = lw2; L.w[3] = lw3;
            bHi = H.v; bLo = L.v;
        }

        // ---- FC: out^T = fc_w @ h5^T + fc_b ----
        bf16x8 f0 = *(const bf16x8*)(s.wF + (0  + n0) * W_ST + q * 8);
        bf16x8 f1 = *(const bf16x8*)(s.wF + (16 + n0) * W_ST + q * 8);
        f32x4 o0 = *(const f32x4*)(s.fb_ + 0  + q * 4);
        f32x4 o1 = *(const f32x4*)(s.fb_ + 16 + q * 4);
        o0 = mfma16(f0, bLo, o0); o0 = mfma16(f0, bHi, o0);
        o1 = mfma16(f1, bLo, o1); o1 = mfma16(f1, bHi, o1);

        // lane holds out[batch = rowBase+n0][emb = t*16 + q*4 + i]
        float* op = out + (size_t)(rowBase + n0) * 32;
        *(f32x4*)(op + 0  + q * 4) = o0;
        *(f32x4*)(op + 16 + q * 4) = o1;
    }
}

extern "C" void kernel_launch(void* const* d_in, const int* in_sizes, int n_in,
                              void* d_out, int out_size, void* d_ws, size_t ws_size,
                              hipStream_t stream) {
    (void)n_in; (void)d_ws; (void)ws_size; (void)out_size;
    const float* x    = (const float*)d_in[0];
    const float* w_ih = (const float*)d_in[1];
    // d_in[2] = w_hh: unused (h0 == 0, T == 1)
    const float* b_ih = (const float*)d_in[3];
    const float* b_hh = (const float*)d_in[4];
    const float* fc_w = (const float*)d_in[5];
    const float* fc_b = (const float*)d_in[6];
    float* out = (float*)d_out;

    const int batch  = in_sizes[0] / 32;   // 1048576
    const int nTiles = batch / 16;         // 65536

    // 768 blocks x 512 thr: 3 blocks/CU (LDS 43.6 KB), 6144 waves,
    // ~10.7 tiles/wave grid-stride.
    gru_fused<<<768, NT, 0, stream>>>(x, w_ih, b_ih, b_hh, fc_w, fc_b, out, nTiles);
}

// Round 5
// 149.679 us; speedup vs baseline: 1.4613x; 1.4613x over previous
//
#include <hip/hip_runtime.h>

// ---------------------------------------------------------------------------
// Fused 5-layer GRU (SEQ=1, h0=0) + FC for MI355X (gfx950).  Round 6.
//
// R6: R5's permlane loop was correct and VALU-neutral (VALU busy-time 106 vs
// 104 us), but __launch_bounds__(512,6) capped the allocator at ~85 VGPRs
// against ~100 live -> ~16 dwords spilled/reloaded per tile = 545 MB of
// scratch HBM traffic (FETCH 66->522 MB) and +76 us of latency.  Restore
// the no-spill regime: __launch_bounds__(512,4) (cap 128), grid 512 blocks
// (2 blocks/CU exact fill).  Everything else unchanged from R5:
//  - per-layer C->B transform in-register via v_permlane32_swap_b32 +
//    v_permlane16_swap_b32 (8 VALU ops replace 6 LDS ops + lgkmcnt wait)
//  - W_ST=40-padded LDS weights ((5*n0+q)%8 uniform bank quads)
//  - packed f32x2 activation math (v_pk_*), split-B bf16 hi+lo precision
//
// Orientation: C^T = W @ h^T  (A = weight tile [gate][k], B = h^T [k][batch]).
// MFMA C/D layout (16x16x32): col = lane&15 = BATCH, row = q*4+i = gate row.
// ---------------------------------------------------------------------------

typedef __attribute__((ext_vector_type(8))) short bf16x8;
typedef __attribute__((ext_vector_type(4))) float f32x4;
typedef __attribute__((ext_vector_type(2))) float f32x2;
typedef __attribute__((ext_vector_type(4))) unsigned int u32x4;

#define NLAYER 5
#define W_ST   40  // weight row stride in bf16 (80 B = 5 bank-quads: conflict-free)
#define NT     512 // block threads (8 waves)

__device__ __forceinline__ float fexp2(float x) {
#if __has_builtin(__builtin_amdgcn_exp2f)
    return __builtin_amdgcn_exp2f(x);
#else
    return exp2f(x);
#endif
}
__device__ __forceinline__ float frcp(float x) {
#if __has_builtin(__builtin_amdgcn_rcpf)
    return __builtin_amdgcn_rcpf(x);
#else
    return 1.0f / x;
#endif
}

__device__ __forceinline__ unsigned short bf_rne(float f) {
    union { float f; unsigned u; } v; v.f = f;
    unsigned r = v.u + 0x7fffu + ((v.u >> 16) & 1u);
    return (unsigned short)(r >> 16);
}

// Truncation-based split: f ~= bf16(hi) + bf16(lo), packing two consecutive
// elements into one hi word and one lo word (low short = even element).
// Combined rel error < 2^-15, negligible vs 2^-8 weight quant.
__device__ __forceinline__ void split2(float f0, float f1, unsigned &hi, unsigned &lo) {
    unsigned u0 = __float_as_uint(f0), u1 = __float_as_uint(f1);
    unsigned h0 = u0 & 0xffff0000u, h1 = u1 & 0xffff0000u;
    hi = (u0 >> 16) | h1;
    float r0 = f0 - __uint_as_float(h0);        // exact
    float r1 = f1 - __uint_as_float(h1);        // exact
    lo = (__float_as_uint(r0) >> 16) | (__float_as_uint(r1) & 0xffff0000u);
}

__device__ __forceinline__ f32x4 mfma16(bf16x8 a, bf16x8 b, f32x4 c) {
    return __builtin_amdgcn_mfma_f32_16x16x32_bf16(a, b, c, 0, 0, 0);
}

// In-register 16-lane-group exchange (gfx950):
//   in : x = [X0,X1,X2,X3], y = [Y0,Y1,Y2,Y3]   (16-lane groups)
//   out: x = [X0,X2,Y0,Y2], y = [X1,X3,Y1,Y3]
__device__ __forceinline__ void xpose_pair(unsigned &x, unsigned &y) {
    asm("v_permlane32_swap_b32 %0, %1" : "+v"(x), "+v"(y));
    asm("v_permlane16_swap_b32 %0, %1" : "+v"(x), "+v"(y));
}

__device__ __forceinline__ f32x2 mk2(float a, float b) { f32x2 v; v.x = a; v.y = b; return v; }
__device__ __forceinline__ f32x2 exp2v(f32x2 v) { f32x2 r; r.x = fexp2(v.x); r.y = fexp2(v.y); return r; }
__device__ __forceinline__ f32x2 rcpv(f32x2 v)  { f32x2 r; r.x = frcp(v.x);  r.y = frcp(v.y);  return r; }

// h = (1-z)*n = sigmoid(-az) * tanh(an + sigmoid(ar)*cn)
//   = [ez*(1-en)] / [(1+ez)*(1+en)],  ez=e^{-az}, en=e^{-2(an+r*cn)}
// Packed 2-wide: non-trans ops lower to v_pk_* VOP3P.
__device__ __forceinline__ f32x2 gru_act2(f32x2 ar, f32x2 az, f32x2 an, f32x2 cn) {
    const float NL2E = -1.4426950408889634f;
    f32x2 er  = exp2v(ar * NL2E);
    f32x2 ez  = exp2v(az * NL2E);
    f32x2 r   = rcpv(er + 1.0f);
    f32x2 a2  = an + r * cn;
    f32x2 en  = exp2v(a2 * (2.0f * NL2E));
    f32x2 num = ez - ez * en;
    f32x2 den = (ez + 1.0f) * (en + 1.0f);
    return num * rcpv(den);
}

struct __align__(16) Lds {
    unsigned short wA[NLAYER * 96 * W_ST];        // 38400 B  [l][gate-row][k], row stride 40
    unsigned short wF[32 * W_ST];                 //  2560 B  fc_w rows, stride 40
    float bsum[NLAYER * 96];                      //  1920 B  r,z: b_ih+b_hh ; n: b_ih only
    float cn_[NLAYER * 32];                       //   640 B  b_hh n-gate
    float fb_[32];                                //   128 B  fc_b
};                                                // total 43648 B

union BU { u32x4 w; bf16x8 v; };

__global__ __launch_bounds__(NT, 4) void gru_fused(
    const float* __restrict__ x, const float* __restrict__ w_ih,
    const float* __restrict__ b_ih, const float* __restrict__ b_hh,
    const float* __restrict__ fc_w, const float* __restrict__ fc_b,
    float* __restrict__ out, int nTiles)
{
    __shared__ Lds s;
    const int tid = threadIdx.x;

    // ---- stage weights / biases into LDS (once per block) ----
    for (int i = tid; i < NLAYER * 96 * 32; i += NT) {
        int r = i >> 5, c = i & 31;
        s.wA[r * W_ST + c] = bf_rne(w_ih[i]);
    }
    for (int i = tid; i < 32 * 32; i += NT) {
        int r = i >> 5, c = i & 31;
        s.wF[r * W_ST + c] = bf_rne(fc_w[i]);
    }
    for (int i = tid; i < NLAYER * 96; i += NT) {
        int c = i % 96;
        s.bsum[i] = b_ih[i] + (c < 64 ? b_hh[i] : 0.0f);
    }
    for (int i = tid; i < NLAYER * 32; i += NT) {
        int l = i >> 5, c = i & 31;
        s.cn_[i] = b_hh[l * 96 + 64 + c];
    }
    if (tid < 32) s.fb_[tid] = fc_b[tid];
    __syncthreads();

    const int lane = tid & 63;
    const int n0 = lane & 15;     // batch-col (B n-index / C col); A row m
    const int q  = lane >> 4;     // k-group (A/B), row-group (C/D)

    const int waveId  = (int)((blockIdx.x * (unsigned)NT + tid) >> 6);
    const int nWavesG = (int)((gridDim.x * (unsigned)NT) >> 6);

    for (int tile = waveId; tile < nTiles; tile += nWavesG) {
        const int rowBase = tile * 16;

        // ---- load x as B-frag: batch = rowBase+n0, k = q*8..q*8+7, split ----
        const float* xp = x + (size_t)(rowBase + n0) * 32 + q * 8;
        f32x4 xa = *(const f32x4*)xp;
        f32x4 xb = *(const f32x4*)(xp + 4);
        BU H, L;
        {
            unsigned th0, tl0, th1, tl1, th2, tl2, th3, tl3;
            split2(xa[0], xa[1], th0, tl0);
            split2(xa[2], xa[3], th1, tl1);
            split2(xb[0], xb[1], th2, tl2);
            split2(xb[2], xb[3], th3, tl3);
            H.w[0] = th0; H.w[1] = th1; H.w[2] = th2; H.w[3] = th3;
            L.w[0] = tl0; L.w[1] = tl1; L.w[2] = tl2; L.w[3] = tl3;
        }
        bf16x8 bHi = H.v, bLo = L.v;

        #pragma unroll
        for (int l = 0; l < NLAYER; ++l) {
            const unsigned short* wb = s.wA + l * 96 * W_ST;
            bf16x8 a0 = *(const bf16x8*)(wb + (0 * 16 + n0) * W_ST + q * 8);
            bf16x8 a1 = *(const bf16x8*)(wb + (1 * 16 + n0) * W_ST + q * 8);
            bf16x8 a2 = *(const bf16x8*)(wb + (2 * 16 + n0) * W_ST + q * 8);
            bf16x8 a3 = *(const bf16x8*)(wb + (3 * 16 + n0) * W_ST + q * 8);
            bf16x8 a4 = *(const bf16x8*)(wb + (4 * 16 + n0) * W_ST + q * 8);
            bf16x8 a5 = *(const bf16x8*)(wb + (5 * 16 + n0) * W_ST + q * 8);

            // acc init = bias f32x4 (rows q*4..q*4+3 of each 16-row gate tile)
            const float* bs = s.bsum + l * 96;
            f32x4 cR0 = *(const f32x4*)(bs + 0  + q * 4);
            f32x4 cR1 = *(const f32x4*)(bs + 16 + q * 4);
            f32x4 cZ0 = *(const f32x4*)(bs + 32 + q * 4);
            f32x4 cZ1 = *(const f32x4*)(bs + 48 + q * 4);
            f32x4 cN0 = *(const f32x4*)(bs + 64 + q * 4);
            f32x4 cN1 = *(const f32x4*)(bs + 80 + q * 4);
            f32x4 vc0 = *(const f32x4*)(s.cn_ + l * 32 + 0  + q * 4);
            f32x4 vc1 = *(const f32x4*)(s.cn_ + l * 32 + 16 + q * 4);

            cR0 = mfma16(a0, bLo, cR0); cR0 = mfma16(a0, bHi, cR0);
            cR1 = mfma16(a1, bLo, cR1); cR1 = mfma16(a1, bHi, cR1);
            cZ0 = mfma16(a2, bLo, cZ0); cZ0 = mfma16(a2, bHi, cZ0);
            cZ1 = mfma16(a3, bLo, cZ1); cZ1 = mfma16(a3, bHi, cZ1);
            cN0 = mfma16(a4, bLo, cN0); cN0 = mfma16(a4, bHi, cN0);
            cN1 = mfma16(a5, bLo, cN1); cN1 = mfma16(a5, bHi, cN1);

            // ---- activations (packed pairs): hid = q*4+i (+16), batch = n0 ----
            f32x2 hA = gru_act2(mk2(cR0[0], cR0[1]), mk2(cZ0[0], cZ0[1]),
                                mk2(cN0[0], cN0[1]), mk2(vc0[0], vc0[1]));
            f32x2 hB = gru_act2(mk2(cR0[2], cR0[3]), mk2(cZ0[2], cZ0[3]),
                                mk2(cN0[2], cN0[3]), mk2(vc0[2], vc0[3]));
            f32x2 hC = gru_act2(mk2(cR1[0], cR1[1]), mk2(cZ1[0], cZ1[1]),
                                mk2(cN1[0], cN1[1]), mk2(vc1[0], vc1[1]));
            f32x2 hD = gru_act2(mk2(cR1[2], cR1[3]), mk2(cZ1[2], cZ1[3]),
                                mk2(cN1[2], cN1[3]), mk2(vc1[2], vc1[3]));

            // ---- pack + in-register C->B transform (no LDS) ----
            // hw0 = hids 4q+{0,1}, hw1 = 4q+{2,3}, hw2 = 16+4q+{0,1}, hw3 = 16+4q+{2,3}
            unsigned hw0, hw1, hw2, hw3, lw0, lw1, lw2, lw3;
            split2(hA.x, hA.y, hw0, lw0);
            split2(hB.x, hB.y, hw1, lw1);
            split2(hC.x, hC.y, hw2, lw2);
            split2(hD.x, hD.y, hw3, lw3);
            xpose_pair(hw0, hw2);   // hw0 -> B elems {0,1}, hw2 -> elems {4,5}
            xpose_pair(hw1, hw3);   // hw1 -> B elems {2,3}, hw3 -> elems {6,7}
            xpose_pair(lw0, lw2);
            xpose_pair(lw1, lw3);
            H.w[0] = hw0; H.w[1] = hw1; H.w[2] = hw2; H.w[3] = hw3;
            L.w[0] = lw0; L.w[1] = lw1; L.w[2] = lw2; L.w[3] = lw3;
            bHi = H.v; bLo = L.v;
        }

        // ---- FC: out^T = fc_w @ h5^T + fc_b ----
        bf16x8 f0 = *(const bf16x8*)(s.wF + (0  + n0) * W_ST + q * 8);
        bf16x8 f1 = *(const bf16x8*)(s.wF + (16 + n0) * W_ST + q * 8);
        f32x4 o0 = *(const f32x4*)(s.fb_ + 0  + q * 4);
        f32x4 o1 = *(const f32x4*)(s.fb_ + 16 + q * 4);
        o0 = mfma16(f0, bLo, o0); o0 = mfma16(f0, bHi, o0);
        o1 = mfma16(f1, bLo, o1); o1 = mfma16(f1, bHi, o1);

        // lane holds out[batch = rowBase+n0][emb = t*16 + q*4 + i]
        float* op = out + (size_t)(rowBase + n0) * 32;
        *(f32x4*)(op + 0  + q * 4) = o0;
        *(f32x4*)(op + 16 + q * 4) = o1;
    }
}

extern "C" void kernel_launch(void* const* d_in, const int* in_sizes, int n_in,
                              void* d_out, int out_size, void* d_ws, size_t ws_size,
                              hipStream_t stream) {
    (void)n_in; (void)d_ws; (void)ws_size; (void)out_size;
    const float* x    = (const float*)d_in[0];
    const float* w_ih = (const float*)d_in[1];
    // d_in[2] = w_hh: unused (h0 == 0, T == 1)
    const float* b_ih = (const float*)d_in[3];
    const float* b_hh = (const float*)d_in[4];
    const float* fc_w = (const float*)d_in[5];
    const float* fc_b = (const float*)d_in[6];
    float* out = (float*)d_out;

    const int batch  = in_sizes[0] / 32;   // 1048576
    const int nTiles = batch / 16;         // 65536

    // 512 blocks x 512 thr: 2 blocks/CU (no-spill VGPR regime), 4096 waves,
    // 16 tiles/wave.
    gru_fused<<<512, NT, 0, stream>>>(x, w_ih, b_ih, b_hh, fc_w, fc_b, out, nTiles);
}

// Round 6
// 140.191 us; speedup vs baseline: 1.5602x; 1.0677x over previous
//
#include <hip/hip_runtime.h>

// ---------------------------------------------------------------------------
// Fused 5-layer GRU (SEQ=1, h0=0) + FC for MI355X (gfx950).  Round 7.
//
// R7: 2-tile interleave per wave.  R6 showed VALU busy-time pinned at
// ~107us with a ~66us stall gap (serial per-layer chain MFMA -> 40 trans ->
// split -> permlane -> MFMA, only 4 waves/SIMD to hide trans latency).
// Two adjacent batch tiles per wave give two independent chains (ILP), and
// share the loop-invariant operands:
//  - A-frags read once per layer, used by 4 MFMAs (2 tiles x hi/lo)
//  - bias acc-init via MFMA D!=C form: accA = mfma(a, bLoA, biasReg) -- no
//    v_mov copies, one LDS read serves both tiles
//  - split2 now via v_cvt_pk_bf16_f32 (gfx950, no builtin -> inline asm):
//    7 ops/pair vs 9, RNE hi halves the residual
// Register budget: ~115 live < 128 cap from __launch_bounds__(512,4); the
// R5 spill tripwire (FETCH_SIZE explosion) guards this.
//
// Kept: permlane C->B transform (R5), W_ST=40 padded LDS weights (R4),
// packed f32x2 activation math (R4), split-B bf16 hi+lo precision.
//
// Orientation: C^T = W @ h^T  (A = weight tile [gate][k], B = h^T [k][batch]).
// MFMA C/D layout (16x16x32): col = lane&15 = BATCH, row = q*4+i = gate row.
// ---------------------------------------------------------------------------

typedef __attribute__((ext_vector_type(8))) short bf16x8;
typedef __attribute__((ext_vector_type(4))) float f32x4;
typedef __attribute__((ext_vector_type(2))) float f32x2;
typedef __attribute__((ext_vector_type(4))) unsigned int u32x4;

#define NLAYER 5
#define W_ST   40  // weight row stride in bf16 (80 B = 5 bank-quads: conflict-free)
#define NT     512 // block threads (8 waves)

__device__ __forceinline__ float fexp2(float x) {
#if __has_builtin(__builtin_amdgcn_exp2f)
    return __builtin_amdgcn_exp2f(x);
#else
    return exp2f(x);
#endif
}
__device__ __forceinline__ float frcp(float x) {
#if __has_builtin(__builtin_amdgcn_rcpf)
    return __builtin_amdgcn_rcpf(x);
#else
    return 1.0f / x;
#endif
}

__device__ __forceinline__ unsigned short bf_rne(float f) {
    union { float f; unsigned u; } v; v.f = f;
    unsigned r = v.u + 0x7fffu + ((v.u >> 16) & 1u);
    return (unsigned short)(r >> 16);
}

// split via v_cvt_pk_bf16_f32: f ~= bf16(hi) + bf16(lo), two elements packed
// per word (low short = even element).  RNE hi -> |residual| <= 2^-9|f|,
// combined error ~2^-18: far below the 2^-8 weight quant floor.
__device__ __forceinline__ void split2(float f0, float f1, unsigned &hi, unsigned &lo) {
    unsigned h, l;
    asm("v_cvt_pk_bf16_f32 %0, %1, %2" : "=v"(h) : "v"(f0), "v"(f1));
    float g0 = __uint_as_float(h << 16);
    float g1 = __uint_as_float(h & 0xffff0000u);
    float r0 = f0 - g0;
    float r1 = f1 - g1;
    asm("v_cvt_pk_bf16_f32 %0, %1, %2" : "=v"(l) : "v"(r0), "v"(r1));
    hi = h; lo = l;
}

__device__ __forceinline__ f32x4 mfma16(bf16x8 a, bf16x8 b, f32x4 c) {
    return __builtin_amdgcn_mfma_f32_16x16x32_bf16(a, b, c, 0, 0, 0);
}

// In-register 16-lane-group exchange (gfx950):
//   in : x = [X0,X1,X2,X3], y = [Y0,Y1,Y2,Y3]   (16-lane groups)
//   out: x = [X0,X2,Y0,Y2], y = [X1,X3,Y1,Y3]
__device__ __forceinline__ void xpose_pair(unsigned &x, unsigned &y) {
    asm("v_permlane32_swap_b32 %0, %1" : "+v"(x), "+v"(y));
    asm("v_permlane16_swap_b32 %0, %1" : "+v"(x), "+v"(y));
}

__device__ __forceinline__ f32x2 mk2(float a, float b) { f32x2 v; v.x = a; v.y = b; return v; }
__device__ __forceinline__ f32x2 exp2v(f32x2 v) { f32x2 r; r.x = fexp2(v.x); r.y = fexp2(v.y); return r; }
__device__ __forceinline__ f32x2 rcpv(f32x2 v)  { f32x2 r; r.x = frcp(v.x);  r.y = frcp(v.y);  return r; }

// h = (1-z)*n = sigmoid(-az) * tanh(an + sigmoid(ar)*cn)
//   = [ez*(1-en)] / [(1+ez)*(1+en)],  ez=e^{-az}, en=e^{-2(an+r*cn)}
// Packed 2-wide: non-trans ops lower to v_pk_* VOP3P.
__device__ __forceinline__ f32x2 gru_act2(f32x2 ar, f32x2 az, f32x2 an, f32x2 cn) {
    const float NL2E = -1.4426950408889634f;
    f32x2 er  = exp2v(ar * NL2E);
    f32x2 ez  = exp2v(az * NL2E);
    f32x2 r   = rcpv(er + 1.0f);
    f32x2 a2  = an + r * cn;
    f32x2 en  = exp2v(a2 * (2.0f * NL2E));
    f32x2 num = ez - ez * en;
    f32x2 den = (ez + 1.0f) * (en + 1.0f);
    return num * rcpv(den);
}

struct __align__(16) Lds {
    unsigned short wA[NLAYER * 96 * W_ST];        // 38400 B  [l][gate-row][k], row stride 40
    unsigned short wF[32 * W_ST];                 //  2560 B  fc_w rows, stride 40
    float bsum[NLAYER * 96];                      //  1920 B  r,z: b_ih+b_hh ; n: b_ih only
    float cn_[NLAYER * 32];                       //   640 B  b_hh n-gate
    float fb_[32];                                //   128 B  fc_b
};                                                // total 43648 B

union BU { u32x4 w; bf16x8 v; };

__global__ __launch_bounds__(NT, 4) void gru_fused(
    const float* __restrict__ x, const float* __restrict__ w_ih,
    const float* __restrict__ b_ih, const float* __restrict__ b_hh,
    const float* __restrict__ fc_w, const float* __restrict__ fc_b,
    float* __restrict__ out, int nPairs)
{
    __shared__ Lds s;
    const int tid = threadIdx.x;

    // ---- stage weights / biases into LDS (once per block) ----
    for (int i = tid; i < NLAYER * 96 * 32; i += NT) {
        int r = i >> 5, c = i & 31;
        s.wA[r * W_ST + c] = bf_rne(w_ih[i]);
    }
    for (int i = tid; i < 32 * 32; i += NT) {
        int r = i >> 5, c = i & 31;
        s.wF[r * W_ST + c] = bf_rne(fc_w[i]);
    }
    for (int i = tid; i < NLAYER * 96; i += NT) {
        int c = i % 96;
        s.bsum[i] = b_ih[i] + (c < 64 ? b_hh[i] : 0.0f);
    }
    for (int i = tid; i < NLAYER * 32; i += NT) {
        int l = i >> 5, c = i & 31;
        s.cn_[i] = b_hh[l * 96 + 64 + c];
    }
    if (tid < 32) s.fb_[tid] = fc_b[tid];
    __syncthreads();

    const int lane = tid & 63;
    const int n0 = lane & 15;     // batch-col (B n-index / C col); A row m
    const int q  = lane >> 4;     // k-group (A/B), row-group (C/D)

    const int waveId  = (int)((blockIdx.x * (unsigned)NT + tid) >> 6);
    const int nWavesG = (int)((gridDim.x * (unsigned)NT) >> 6);

    for (int t = waveId; t < nPairs; t += nWavesG) {
        const int rowBase = t * 32;  // tile A rows +0..15, tile B rows +16..31

        // ---- load x as B-frags for both tiles, split hi/lo ----
        const float* xpA = x + (size_t)(rowBase + n0) * 32 + q * 8;
        const float* xpB = x + (size_t)(rowBase + 16 + n0) * 32 + q * 8;
        f32x4 xaA = *(const f32x4*)xpA, xbA = *(const f32x4*)(xpA + 4);
        f32x4 xaB = *(const f32x4*)xpB, xbB = *(const f32x4*)(xpB + 4);
        BU HA, LA, HB, LB;
        {
            unsigned h0, l0, h1, l1, h2, l2, h3, l3;
            split2(xaA[0], xaA[1], h0, l0); split2(xaA[2], xaA[3], h1, l1);
            split2(xbA[0], xbA[1], h2, l2); split2(xbA[2], xbA[3], h3, l3);
            HA.w[0] = h0; HA.w[1] = h1; HA.w[2] = h2; HA.w[3] = h3;
            LA.w[0] = l0; LA.w[1] = l1; LA.w[2] = l2; LA.w[3] = l3;
            split2(xaB[0], xaB[1], h0, l0); split2(xaB[2], xaB[3], h1, l1);
            split2(xbB[0], xbB[1], h2, l2); split2(xbB[2], xbB[3], h3, l3);
            HB.w[0] = h0; HB.w[1] = h1; HB.w[2] = h2; HB.w[3] = h3;
            LB.w[0] = l0; LB.w[1] = l1; LB.w[2] = l2; LB.w[3] = l3;
        }
        bf16x8 bHiA = HA.v, bLoA = LA.v, bHiB = HB.v, bLoB = LB.v;

        #pragma unroll
        for (int l = 0; l < NLAYER; ++l) {
            const unsigned short* wb = s.wA + l * 96 * W_ST;
            const float* bs = s.bsum + l * 96;

            f32x4 cR0A, cR1A, cZ0A, cZ1A, cN0A, cN1A;
            f32x4 cR0B, cR1B, cZ0B, cZ1B, cN0B, cN1B;

            // per gate-tile: 1 A-frag LDS read + 1 bias LDS read -> 4 MFMAs.
            // first MFMA uses D != C to init from the shared bias register.
            {
                bf16x8 a = *(const bf16x8*)(wb + (0 * 16 + n0) * W_ST + q * 8);
                f32x4 cb = *(const f32x4*)(bs + 0 + q * 4);
                cR0A = mfma16(a, bLoA, cb); cR0A = mfma16(a, bHiA, cR0A);
                cR0B = mfma16(a, bLoB, cb); cR0B = mfma16(a, bHiB, cR0B);
            }
            {
                bf16x8 a = *(const bf16x8*)(wb + (1 * 16 + n0) * W_ST + q * 8);
                f32x4 cb = *(const f32x4*)(bs + 16 + q * 4);
                cR1A = mfma16(a, bLoA, cb); cR1A = mfma16(a, bHiA, cR1A);
                cR1B = mfma16(a, bLoB, cb); cR1B = mfma16(a, bHiB, cR1B);
            }
            {
                bf16x8 a = *(const bf16x8*)(wb + (2 * 16 + n0) * W_ST + q * 8);
                f32x4 cb = *(const f32x4*)(bs + 32 + q * 4);
                cZ0A = mfma16(a, bLoA, cb); cZ0A = mfma16(a, bHiA, cZ0A);
                cZ0B = mfma16(a, bLoB, cb); cZ0B = mfma16(a, bHiB, cZ0B);
            }
            {
                bf16x8 a = *(const bf16x8*)(wb + (3 * 16 + n0) * W_ST + q * 8);
                f32x4 cb = *(const f32x4*)(bs + 48 + q * 4);
                cZ1A = mfma16(a, bLoA, cb); cZ1A = mfma16(a, bHiA, cZ1A);
                cZ1B = mfma16(a, bLoB, cb); cZ1B = mfma16(a, bHiB, cZ1B);
            }
            {
                bf16x8 a = *(const bf16x8*)(wb + (4 * 16 + n0) * W_ST + q * 8);
                f32x4 cb = *(const f32x4*)(bs + 64 + q * 4);
                cN0A = mfma16(a, bLoA, cb); cN0A = mfma16(a, bHiA, cN0A);
                cN0B = mfma16(a, bLoB, cb); cN0B = mfma16(a, bHiB, cN0B);
            }
            {
                bf16x8 a = *(const bf16x8*)(wb + (5 * 16 + n0) * W_ST + q * 8);
                f32x4 cb = *(const f32x4*)(bs + 80 + q * 4);
                cN1A = mfma16(a, bLoA, cb); cN1A = mfma16(a, bHiA, cN1A);
                cN1B = mfma16(a, bLoB, cb); cN1B = mfma16(a, bHiB, cN1B);
            }

            f32x4 vc0 = *(const f32x4*)(s.cn_ + l * 32 + 0  + q * 4);
            f32x4 vc1 = *(const f32x4*)(s.cn_ + l * 32 + 16 + q * 4);

            // ---- activations + pack + permlane transform, tile A ----
            {
                f32x2 hA = gru_act2(mk2(cR0A[0], cR0A[1]), mk2(cZ0A[0], cZ0A[1]),
                                    mk2(cN0A[0], cN0A[1]), mk2(vc0[0], vc0[1]));
                f32x2 hB = gru_act2(mk2(cR0A[2], cR0A[3]), mk2(cZ0A[2], cZ0A[3]),
                                    mk2(cN0A[2], cN0A[3]), mk2(vc0[2], vc0[3]));
                f32x2 hC = gru_act2(mk2(cR1A[0], cR1A[1]), mk2(cZ1A[0], cZ1A[1]),
                                    mk2(cN1A[0], cN1A[1]), mk2(vc1[0], vc1[1]));
                f32x2 hD = gru_act2(mk2(cR1A[2], cR1A[3]), mk2(cZ1A[2], cZ1A[3]),
                                    mk2(cN1A[2], cN1A[3]), mk2(vc1[2], vc1[3]));
                unsigned hw0, hw1, hw2, hw3, lw0, lw1, lw2, lw3;
                split2(hA.x, hA.y, hw0, lw0);
                split2(hB.x, hB.y, hw1, lw1);
                split2(hC.x, hC.y, hw2, lw2);
                split2(hD.x, hD.y, hw3, lw3);
                xpose_pair(hw0, hw2); xpose_pair(hw1, hw3);
                xpose_pair(lw0, lw2); xpose_pair(lw1, lw3);
                HA.w[0] = hw0; HA.w[1] = hw1; HA.w[2] = hw2; HA.w[3] = hw3;
                LA.w[0] = lw0; LA.w[1] = lw1; LA.w[2] = lw2; LA.w[3] = lw3;
                bHiA = HA.v; bLoA = LA.v;
            }
            // ---- activations + pack + permlane transform, tile B ----
            {
                f32x2 hA = gru_act2(mk2(cR0B[0], cR0B[1]), mk2(cZ0B[0], cZ0B[1]),
                                    mk2(cN0B[0], cN0B[1]), mk2(vc0[0], vc0[1]));
                f32x2 hB = gru_act2(mk2(cR0B[2], cR0B[3]), mk2(cZ0B[2], cZ0B[3]),
                                    mk2(cN0B[2], cN0B[3]), mk2(vc0[2], vc0[3]));
                f32x2 hC = gru_act2(mk2(cR1B[0], cR1B[1]), mk2(cZ1B[0], cZ1B[1]),
                                    mk2(cN1B[0], cN1B[1]), mk2(vc1[0], vc1[1]));
                f32x2 hD = gru_act2(mk2(cR1B[2], cR1B[3]), mk2(cZ1B[2], cZ1B[3]),
                                    mk2(cN1B[2], cN1B[3]), mk2(vc1[2], vc1[3]));
                unsigned hw0, hw1, hw2, hw3, lw0, lw1, lw2, lw3;
                split2(hA.x, hA.y, hw0, lw0);
                split2(hB.x, hB.y, hw1, lw1);
                split2(hC.x, hC.y, hw2, lw2);
                split2(hD.x, hD.y, hw3, lw3);
                xpose_pair(hw0, hw2); xpose_pair(hw1, hw3);
                xpose_pair(lw0, lw2); xpose_pair(lw1, lw3);
                HB.w[0] = hw0; HB.w[1] = hw1; HB.w[2] = hw2; HB.w[3] = hw3;
                LB.w[0] = lw0; LB.w[1] = lw1; LB.w[2] = lw2; LB.w[3] = lw3;
                bHiB = HB.v; bLoB = LB.v;
            }
        }

        // ---- FC: out^T = fc_w @ h5^T + fc_b, both tiles ----
        bf16x8 f0 = *(const bf16x8*)(s.wF + (0  + n0) * W_ST + q * 8);
        bf16x8 f1 = *(const bf16x8*)(s.wF + (16 + n0) * W_ST + q * 8);
        f32x4 ob0 = *(const f32x4*)(s.fb_ + 0  + q * 4);
        f32x4 ob1 = *(const f32x4*)(s.fb_ + 16 + q * 4);
        f32x4 o0A = mfma16(f0, bLoA, ob0); o0A = mfma16(f0, bHiA, o0A);
        f32x4 o1A = mfma16(f1, bLoA, ob1); o1A = mfma16(f1, bHiA, o1A);
        f32x4 o0B = mfma16(f0, bLoB, ob0); o0B = mfma16(f0, bHiB, o0B);
        f32x4 o1B = mfma16(f1, bLoB, ob1); o1B = mfma16(f1, bHiB, o1B);

        // lane holds out[batch][emb = t*16 + q*4 + i]
        float* opA = out + (size_t)(rowBase + n0) * 32;
        float* opB = out + (size_t)(rowBase + 16 + n0) * 32;
        *(f32x4*)(opA + 0  + q * 4) = o0A;
        *(f32x4*)(opA + 16 + q * 4) = o1A;
        *(f32x4*)(opB + 0  + q * 4) = o0B;
        *(f32x4*)(opB + 16 + q * 4) = o1B;
    }
}

extern "C" void kernel_launch(void* const* d_in, const int* in_sizes, int n_in,
                              void* d_out, int out_size, void* d_ws, size_t ws_size,
                              hipStream_t stream) {
    (void)n_in; (void)d_ws; (void)ws_size; (void)out_size;
    const float* x    = (const float*)d_in[0];
    const float* w_ih = (const float*)d_in[1];
    // d_in[2] = w_hh: unused (h0 == 0, T == 1)
    const float* b_ih = (const float*)d_in[3];
    const float* b_hh = (const float*)d_in[4];
    const float* fc_w = (const float*)d_in[5];
    const float* fc_b = (const float*)d_in[6];
    float* out = (float*)d_out;

    const int batch  = in_sizes[0] / 32;   // 1048576
    const int nPairs = batch / 32;         // 32768 tile-pairs (2 x 16 rows)

    // 512 blocks x 512 thr: 2 blocks/CU, 4096 waves, 8 pairs/wave.
    gru_fused<<<512, NT, 0, stream>>>(x, w_ih, b_ih, b_hh, fc_w, fc_b, out, nPairs);
}